// Round 1
// baseline (1111.197 us; speedup 1.0000x reference)
//
#include <hip/hip_runtime.h>
#include <hip/hip_bf16.h>
#include <hip/hip_cooperative_groups.h>
#include <math.h>

namespace cg = cooperative_groups;

#define N_NODES 20000
#define N_EDGES 320000
#define IN_DIM 128
#define HID 256
#define HEADS 8
#define DH 32
#define LAYERS 3
#define NUM_GRAPHS 64
#define OUT_DIM 10
#define SLOPE 0.2f

// src-bucketed CSR: bucket = src >> 12 (4096 nodes = 2 MB of fsb per bucket)
#define NBKT 5
#define N_BINS (N_NODES * NBKT)
#define N_SCB ((N_BINS + 255) / 256)          // 391 scan blocks of 256 bins

#define NT_GEMM 626                            // 313 m-tiles x 2 n-tiles
#define NE_CHUNKS 1250                         // 320000 / 256 edge chunks
#define NAGG (N_NODES / 8)                     // 2500
#define NPOOL ((N_NODES + 31) / 32)            // 625

typedef __bf16 bf16x8 __attribute__((ext_vector_type(8)));
typedef float f32x4 __attribute__((ext_vector_type(4)));

static __device__ __forceinline__ unsigned short f2bfbits(float v) {
    __bf16 b = (__bf16)v;
    return __builtin_bit_cast(unsigned short, b);
}
// unpack 8 bf16 (in a uint4) -> 8 fp32, exact
static __device__ __forceinline__ void unpack8(uint4 u, float* f) {
    unsigned p0 = u.x, p1 = u.y, p2 = u.z, p3 = u.w;
    f[0] = __builtin_bit_cast(float, p0 << 16);
    f[1] = __builtin_bit_cast(float, p0 & 0xffff0000u);
    f[2] = __builtin_bit_cast(float, p1 << 16);
    f[3] = __builtin_bit_cast(float, p1 & 0xffff0000u);
    f[4] = __builtin_bit_cast(float, p2 << 16);
    f[5] = __builtin_bit_cast(float, p2 & 0xffff0000u);
    f[6] = __builtin_bit_cast(float, p3 << 16);
    f[7] = __builtin_bit_cast(float, p3 & 0xffff0000u);
}

// async 16B global->LDS (DMA, wave-uniform LDS base + lane*16)
typedef const __attribute__((address_space(1))) unsigned int* as1_u32p;
typedef __attribute__((address_space(3))) unsigned int* as3_u32p;
static __device__ __forceinline__ void async_cp16(const unsigned short* g, unsigned short* l) {
    __builtin_amdgcn_global_load_lds((as1_u32p)g, (as3_u32p)l, 16, 0, 0);
}

// ---------------- prep: zero cnt+hg, feature cast, weight transpose/cast ----------------
#define CAST_N4 (N_NODES * IN_DIM / 4)
#define WTRANS_TOTAL (IN_DIM * HID + 6 * HID * HID)
#define ZERO_TOTAL (N_BINS + NUM_GRAPHS * HID)
#define PREP_TOTAL (CAST_N4 + WTRANS_TOTAL + ZERO_TOTAL)

static __device__ void prep_item(int idx,
                                 const float* __restrict__ feat,
                                 const float* __restrict__ Win,
                                 const float* __restrict__ Wsrc,
                                 const float* __restrict__ Wdst,
                                 unsigned short* __restrict__ featH,
                                 unsigned short* __restrict__ WinT,
                                 unsigned short* __restrict__ WT,
                                 int* __restrict__ cnt, float* __restrict__ hg) {
    if (idx < CAST_N4) {
        float4 v = ((const float4*)feat)[idx];
        ushort4 o;
        o.x = f2bfbits(v.x); o.y = f2bfbits(v.y);
        o.z = f2bfbits(v.z); o.w = f2bfbits(v.w);
        ((ushort4*)featH)[idx] = o;
    } else if (idx < CAST_N4 + WTRANS_TOTAL) {
        int j = idx - CAST_N4;
        if (j < IN_DIM * HID) {
            int n = j / IN_DIM, k = j % IN_DIM;
            WinT[j] = f2bfbits(Win[k * HID + n]);
        } else {
            int r6 = j - IN_DIM * HID;
            int mat = r6 >> 16;
            int r = r6 & 65535;
            int n = r >> 8, k = r & 255;
            const float* base = (mat < 3) ? (Wsrc + (size_t)mat * 65536)
                                          : (Wdst + (size_t)(mat - 3) * 65536);
            WT[r6] = f2bfbits(base[k * 256 + n]);
        }
    } else if (idx < PREP_TOTAL) {
        int z = idx - CAST_N4 - WTRANS_TOTAL;
        if (z < N_BINS) cnt[z] = 0;
        else hg[z - N_BINS] = 0.f;
    }
}

// ---------------- 256-thread scan units (hierarchical over 100k bins) ----------------
static __device__ void scanp_unit(int u, int t, const int* __restrict__ cnt,
                                  int* __restrict__ bsum, int* si) {
    int idx = u * 256 + t;
    int x = (idx < N_BINS) ? cnt[idx] : 0;
#pragma unroll
    for (int d = 1; d < 64; d <<= 1) x += __shfl_xor(x, d, 64);
    if ((t & 63) == 0) si[t >> 6] = x;
    __syncthreads();
    if (t == 0) bsum[u] = si[0] + si[1] + si[2] + si[3];
    __syncthreads();
}

static __device__ void scans_unit(int u, int t, const int* __restrict__ cnt,
                                  const int* __restrict__ bsum, int* __restrict__ offs,
                                  int* __restrict__ cursor, int* si) {
    // base = sum of bsum[0..u)
    int bv = 0;
    if (t < u) bv = bsum[t];
    if (t + 256 < u) bv += bsum[t + 256];
#pragma unroll
    for (int d = 1; d < 64; d <<= 1) bv += __shfl_xor(bv, d, 64);
    if ((t & 63) == 0) si[t >> 6] = bv;
    __syncthreads();
    int sbase = si[0] + si[1] + si[2] + si[3];
    __syncthreads();
    // block-local exclusive scan of 256 bins
    int idx = u * 256 + t;
    int x = (idx < N_BINS) ? cnt[idx] : 0;
    int v = x;
#pragma unroll
    for (int d = 1; d < 64; d <<= 1) {
        int w = __shfl_up(v, d, 64);
        if ((t & 63) >= d) v += w;
    }
    if ((t & 63) == 63) si[t >> 6] = v;
    __syncthreads();
    int woff = 0;
#pragma unroll
    for (int w2 = 0; w2 < 4; ++w2) if (w2 < (t >> 6)) woff += si[w2];
    int ex = sbase + woff + v - x;
    if (idx < N_BINS) { offs[idx] = ex; cursor[idx] = ex; }
    if (u == N_SCB - 1 && t == 255) offs[N_BINS] = ex + x;   // grand total (x==0 here)
    __syncthreads();
}

// ---------------- MFMA GEMM tile: bf16 A, M64 x N128, BK=32 (unchanged math) ----------------
template <int DUAL>
static __device__ void gemm_tile(int mt, int nt, int t,
                                 const unsigned short* __restrict__ Ah,
                                 const unsigned short* __restrict__ BT1,
                                 const float* __restrict__ bias1,
                                 unsigned short* __restrict__ O1,
                                 const unsigned short* __restrict__ BT2,
                                 const float* __restrict__ bias2,
                                 unsigned short* __restrict__ O2,
                                 int M, int K, int N,
                                 unsigned short* AsP, unsigned short* Bs1P,
                                 unsigned short* Bs2P) {
    const int wv = t >> 6, lane = t & 63, quad = lane >> 4, l15 = lane & 15;
    const int m0 = mt * 64, n0 = nt * 128;

    const int sA = wv * 64 + lane;
    const int rA = sA >> 2, cA = (sA & 3) ^ ((rA >> 1) & 3);
    int gmA = m0 + rA; if (gmA >= M) gmA = M - 1;
    const size_t offA = (size_t)gmA * K + cA * 8;
    const int sB0 = wv * 64 + lane, sB1v = sB0 + 256;
    const int rB0 = sB0 >> 2, cB0 = (sB0 & 3) ^ ((rB0 >> 1) & 3);
    const int rB1 = sB1v >> 2, cB1 = (sB1v & 3) ^ ((rB1 >> 1) & 3);
    const size_t offB0 = (size_t)(n0 + rB0) * K + cB0 * 8;
    const size_t offB1 = (size_t)(n0 + rB1) * K + cB1 * 8;

    auto issue = [&](int buf, int k0) {
        async_cp16(Ah + offA + k0, AsP + buf * 2048 + wv * 512);
        async_cp16(BT1 + offB0 + k0, Bs1P + buf * 4096 + wv * 512);
        async_cp16(BT1 + offB1 + k0, Bs1P + buf * 4096 + 2048 + wv * 512);
        if (DUAL) {
            async_cp16(BT2 + offB0 + k0, Bs2P + buf * 4096 + wv * 512);
            async_cp16(BT2 + offB1 + k0, Bs2P + buf * 4096 + 2048 + wv * 512);
        }
    };

    const int mrow0 = (wv >> 1) * 32;
    const int ncb = (wv & 1) * 64;

    f32x4 zero = {0.f, 0.f, 0.f, 0.f};
    f32x4 acc1[2][4], acc2[2][4];
#pragma unroll
    for (int mi = 0; mi < 2; ++mi)
#pragma unroll
        for (int t4 = 0; t4 < 4; ++t4) { acc1[mi][t4] = zero; acc2[mi][t4] = zero; }

    issue(0, 0);
    int buf = 0;
    for (int k0 = 0; k0 < K; k0 += 32, buf ^= 1) {
        __syncthreads();
        if (k0 + 32 < K) issue(buf ^ 1, k0 + 32);

        bf16x8 aF[2];
#pragma unroll
        for (int mi = 0; mi < 2; ++mi) {
            int row = mrow0 + mi * 16 + l15;
            int aoff = row * 32 + ((quad ^ ((row >> 1) & 3)) << 3);
            aF[mi] = __builtin_bit_cast(bf16x8, *(const uint4*)(AsP + buf * 2048 + aoff));
        }
#pragma unroll
        for (int t4 = 0; t4 < 4; ++t4) {
            int brow = ncb + t4 * 16 + l15;
            int boff = brow * 32 + ((quad ^ ((brow >> 1) & 3)) << 3);
            bf16x8 b1 = __builtin_bit_cast(bf16x8, *(const uint4*)(Bs1P + buf * 4096 + boff));
#pragma unroll
            for (int mi = 0; mi < 2; ++mi)
                acc1[mi][t4] = __builtin_amdgcn_mfma_f32_16x16x32_bf16(aF[mi], b1, acc1[mi][t4], 0, 0, 0);
            if (DUAL) {
                bf16x8 b2 = __builtin_bit_cast(bf16x8, *(const uint4*)(Bs2P + buf * 4096 + boff));
#pragma unroll
                for (int mi = 0; mi < 2; ++mi)
                    acc2[mi][t4] = __builtin_amdgcn_mfma_f32_16x16x32_bf16(aF[mi], b2, acc2[mi][t4], 0, 0, 0);
            }
        }
    }

    float bia1[4], bia2[4];
#pragma unroll
    for (int t4 = 0; t4 < 4; ++t4) {
        bia1[t4] = bias1[n0 + ncb + t4 * 16 + l15];
        bia2[t4] = DUAL ? bias2[n0 + ncb + t4 * 16 + l15] : 0.f;
    }
#pragma unroll
    for (int mi = 0; mi < 2; ++mi) {
#pragma unroll
        for (int t4 = 0; t4 < 4; ++t4) {
            int gn = n0 + ncb + t4 * 16 + l15;
#pragma unroll
            for (int r = 0; r < 4; ++r) {
                int gm = m0 + mrow0 + mi * 16 + quad * 4 + r;
                if (gm < M) {
                    float v = acc1[mi][t4][r] + bia1[t4];
                    O1[(size_t)gm * N + gn] = f2bfbits(v);
                    if (DUAL) {
                        float v2 = acc2[mi][t4][r] + bia2[t4];
                        O2[(size_t)gm * N + gn] = f2bfbits(v2);
                    }
                }
            }
        }
    }
}

// ---------------- GATv2 aggregation unit (unchanged math, 8 nodes / 256 threads) ----------------
static __device__ void agg_unit(int u, int t,
                                const unsigned short* __restrict__ fsb,
                                const unsigned short* __restrict__ fdb,
                                unsigned short* __restrict__ hb,
                                const int* __restrict__ offs,
                                const int* __restrict__ csr_src,
                                const float* __restrict__ attn_l) {
    int node = u * 8 + (t >> 5);
    if (node >= N_NODES) return;
    int l32 = t & 31;
    int dbase = l32 * 8;
    int abase = (l32 >> 2) * DH + (l32 & 3) * 8;

    float a[8];
#pragma unroll
    for (int j = 0; j < 8; ++j) a[j] = attn_l[abase + j];

    float fdv[8];
    unpack8(*(const uint4*)(fdb + (size_t)node * HID + dbase), fdv);

    float ssum0 = 0.f, ssum1 = 0.f;
    float acc0[8], acc1[8];
#pragma unroll
    for (int j = 0; j < 8; ++j) { acc0[j] = 0.f; acc1[j] = 0.f; }

    auto procE = [&](uint4 uu, float* acc, float& ssum) {
        float fsv[8];
        unpack8(uu, fsv);
        float p = 0.f;
#pragma unroll
        for (int j = 0; j < 8; ++j) {
            float e = fsv[j] + fdv[j];
            e = fmaxf(e, SLOPE * e);   // leakyrelu (slope<1)
            p += e * a[j];
        }
        p += __shfl_xor(p, 1, 64);
        p += __shfl_xor(p, 2, 64);
        float w = __expf(p);
        ssum += w;
#pragma unroll
        for (int j = 0; j < 8; ++j) acc[j] += w * fsv[j];
    };

    const unsigned short* fsl = fsb + dbase;
    int beg = offs[node * NBKT], end = offs[node * NBKT + NBKT];
    int nfull = (end - beg) >> 2;
    const int limit = beg + nfull * 4;

    uint4 cu0, cu1, cu2, cu3;
    int ci0, ci1, ci2, ci3;
    int base = beg + 8;
    bool have = (nfull >= 1);
    bool haveN = (nfull >= 2);
    if (have) {
        int s0 = csr_src[beg], s1 = csr_src[beg + 1];
        int s2 = csr_src[beg + 2], s3 = csr_src[beg + 3];
        if (haveN) {
            ci0 = csr_src[beg + 4]; ci1 = csr_src[beg + 5];
            ci2 = csr_src[beg + 6]; ci3 = csr_src[beg + 7];
        }
        cu0 = *(const uint4*)(fsl + (size_t)s0 * HID);
        cu1 = *(const uint4*)(fsl + (size_t)s1 * HID);
        cu2 = *(const uint4*)(fsl + (size_t)s2 * HID);
        cu3 = *(const uint4*)(fsl + (size_t)s3 * HID);
    }
    while (have) {
        uint4 nu0, nu1, nu2, nu3;
        int ni0, ni1, ni2, ni3;
        if (haveN) {
            nu0 = *(const uint4*)(fsl + (size_t)ci0 * HID);
            nu1 = *(const uint4*)(fsl + (size_t)ci1 * HID);
            nu2 = *(const uint4*)(fsl + (size_t)ci2 * HID);
            nu3 = *(const uint4*)(fsl + (size_t)ci3 * HID);
        }
        bool haveNN = (base + 4 <= limit);
        if (haveNN) {
            ni0 = csr_src[base]; ni1 = csr_src[base + 1];
            ni2 = csr_src[base + 2]; ni3 = csr_src[base + 3];
        }
        base += 4;
        procE(cu0, acc0, ssum0);
        procE(cu1, acc1, ssum1);
        procE(cu2, acc0, ssum0);
        procE(cu3, acc1, ssum1);
        if (haveN) { cu0 = nu0; cu1 = nu1; cu2 = nu2; cu3 = nu3; }
        if (haveNN) { ci0 = ni0; ci1 = ni1; ci2 = ni2; ci3 = ni3; }
        have = haveN; haveN = haveNN;
    }
    for (int idx = limit; idx < end; ++idx) {
        int sv = csr_src[idx];
        procE(*(const uint4*)(fsl + (size_t)sv * HID), acc0, ssum0);
    }

    float ssum = ssum0 + ssum1;
    float acc[8];
#pragma unroll
    for (int j = 0; j < 8; ++j) acc[j] = acc0[j] + acc1[j];

    float inv = ssum > 0.f ? 1.f / ssum : 0.f;
    float hv[8];
    unpack8(*(const uint4*)(hb + (size_t)node * HID + dbase), hv);
    unsigned short ob[8];
#pragma unroll
    for (int j = 0; j < 8; ++j) {
        float o = fmaxf(acc[j] * inv + hv[j], 0.f);
        ob[j] = f2bfbits(o);
    }
    *(uint4*)(hb + (size_t)node * HID + dbase) = *(uint4*)ob;
}

// ---------------- graph sum-pool unit: 32 nodes / 256 threads (1 feature per thread) ----------------
static __device__ void pool_unit(int u, int t, const unsigned short* __restrict__ hb,
                                 const int* __restrict__ gid, float* __restrict__ hg) {
    int n0 = u * 32;
    int n1 = n0 + 32; if (n1 > N_NODES) n1 = N_NODES;
    if (n0 >= N_NODES) return;
    float acc = 0.f;
    int cur = gid[n0];
    for (int n = n0; n < n1; ++n) {
        int g = gid[n];
        if (g != cur) {
            atomicAdd(&hg[(size_t)cur * HID + t], acc);
            acc = 0.f;
            cur = g;
        }
        unsigned v = hb[(size_t)n * HID + t];
        acc += __builtin_bit_cast(float, v << 16);
    }
    atomicAdd(&hg[(size_t)cur * HID + t], acc);
}

// ---------------- classifier unit: one graph / 256 threads ----------------
static __device__ void cls_unit(int g, int t, float* sf, const float* __restrict__ hg,
                                const float* __restrict__ Wc1, const float* __restrict__ bc1,
                                const float* __restrict__ Wc2, const float* __restrict__ bc2,
                                const float* __restrict__ Wc3, const float* __restrict__ bc3,
                                float* __restrict__ out) {
    float* xin = sf;
    float* x1 = sf + HID;
    float* x2 = sf + 2 * HID;
    xin[t] = hg[(size_t)g * HID + t];
    __syncthreads();
    {
        float acc = bc1[t];
        for (int k = 0; k < HID; ++k) acc += xin[k] * Wc1[k * HID + t];
        x1[t] = fmaxf(acc, 0.f);
    }
    __syncthreads();
    if (t < HID / 2) {
        float acc = bc2[t];
        for (int k = 0; k < HID; ++k) acc += x1[k] * Wc2[k * (HID / 2) + t];
        x2[t] = fmaxf(acc, 0.f);
    }
    __syncthreads();
    if (t < OUT_DIM) {
        float acc = bc3[t];
        for (int k = 0; k < HID / 2; ++k) acc += x2[k] * Wc3[k * OUT_DIM + t];
        out[g * OUT_DIM + t] = acc;
    }
    __syncthreads();
}

// ---------------- persistent cooperative mega-kernel ----------------
struct MegaParams {
    const float* feature; const float* W_in; const float* b_in;
    const float* W_src; const float* b_src; const float* W_dst; const float* b_dst;
    const float* attn;
    const float* Wc1; const float* bc1; const float* Wc2; const float* bc2;
    const float* Wc3; const float* bc3;
    const int* src; const int* dst; const int* gid;
    float* out;
    unsigned short* hb; unsigned short* fsb; unsigned short* fdb;
    float* hg; int* cnt; int* offs; int* cursor; int* csr_src; int* bsum;
    unsigned short* WinT; unsigned short* WT; unsigned short* featH;
};

__global__ __launch_bounds__(256, 4) void mega_kernel(MegaParams P) {
    cg::grid_group gg = cg::this_grid();
    __shared__ __align__(16) unsigned short smem[20480];   // 40 KB, reused per phase
    unsigned short* AsP  = smem;          // 2 x 2048 elems (8 KB)
    unsigned short* Bs1P = smem + 4096;   // 2 x 4096 elems (16 KB)
    unsigned short* Bs2P = smem + 12288;  // 2 x 4096 elems (16 KB)
    int* si = (int*)(void*)smem;          // scan scratch (4 ints)
    float* sf = (float*)(void*)smem;      // classifier scratch (640 floats)

    const int t = threadIdx.x;
    const int bid = blockIdx.x;
    const int nblk = gridDim.x;

    // ---- P0: prep (zero cnt+hg, feature cast, weight transposes) ----
    for (int idx = bid * 256 + t; idx < PREP_TOTAL; idx += nblk * 256)
        prep_item(idx, P.feature, P.W_in, P.W_src, P.W_dst, P.featH, P.WinT, P.WT, P.cnt, P.hg);
    gg.sync();

    // ---- P1: input-projection GEMM  ||  edge-bin count ----
    for (int u = bid; u < NT_GEMM + NE_CHUNKS; u += nblk) {
        if (u < NT_GEMM)
            gemm_tile<0>(u >> 1, u & 1, t, P.featH, P.WinT, P.b_in, P.hb,
                         (const unsigned short*)nullptr, (const float*)nullptr,
                         (unsigned short*)nullptr, N_NODES, IN_DIM, HID, AsP, Bs1P, Bs2P);
        else {
            int e = (u - NT_GEMM) * 256 + t;
            if (e < N_EDGES) atomicAdd(&P.cnt[P.dst[e] * NBKT + (P.src[e] >> 12)], 1);
        }
    }
    gg.sync();

    // ---- P2: scan partial sums  ||  layer-0 dual GEMM ----
    for (int u = bid; u < N_SCB + NT_GEMM; u += nblk) {
        if (u < N_SCB) scanp_unit(u, t, P.cnt, P.bsum, si);
        else {
            int g = u - N_SCB;
            gemm_tile<1>(g >> 1, g & 1, t, P.hb, P.WT, P.b_src, P.fsb,
                         P.WT + 3 * 65536, P.b_dst, P.fdb, N_NODES, HID, HID, AsP, Bs1P, Bs2P);
        }
    }
    gg.sync();

    // ---- P3: scan scatter (offs + cursor) ----
    for (int u = bid; u < N_SCB; u += nblk)
        scans_unit(u, t, P.cnt, P.bsum, P.offs, P.cursor, si);
    gg.sync();

    // ---- P4: fill CSR ----
    for (int u = bid; u < NE_CHUNKS; u += nblk) {
        int e = u * 256 + t;
        if (e < N_EDGES) {
            int sv = P.src[e];
            int p = atomicAdd(&P.cursor[P.dst[e] * NBKT + (sv >> 12)], 1);
            P.csr_src[p] = sv;
        }
    }
    gg.sync();

    // ---- layers: agg(l) ; gemm(l+1) ----
    for (int l = 0; l < LAYERS; ++l) {
        for (int u = bid; u < NAGG; u += nblk)
            agg_unit(u, t, P.fsb, P.fdb, P.hb, P.offs, P.csr_src,
                     P.attn + (size_t)l * HEADS * DH);
        gg.sync();
        if (l + 1 < LAYERS) {
            for (int u = bid; u < NT_GEMM; u += nblk)
                gemm_tile<1>(u >> 1, u & 1, t, P.hb,
                             P.WT + (size_t)(l + 1) * 65536, P.b_src + (l + 1) * HID, P.fsb,
                             P.WT + (size_t)(4 + l) * 65536, P.b_dst + (l + 1) * HID, P.fdb,
                             N_NODES, HID, HID, AsP, Bs1P, Bs2P);
            gg.sync();
        }
    }

    // ---- pool ----
    for (int u = bid; u < NPOOL; u += nblk)
        pool_unit(u, t, P.hb, P.gid, P.hg);
    gg.sync();

    // ---- classifier ----
    for (int u = bid; u < NUM_GRAPHS; u += nblk)
        cls_unit(u, t, sf, P.hg, P.Wc1, P.bc1, P.Wc2, P.bc2, P.Wc3, P.bc3, P.out);
}

// ---------------- fallback wrappers (13-dispatch path, bit-identical math) ----------------
__global__ void prep_kernel(const float* feat, const float* Win, const float* Wsrc,
                            const float* Wdst, unsigned short* featH, unsigned short* WinT,
                            unsigned short* WT, int* cnt, float* hg) {
    prep_item(blockIdx.x * blockDim.x + threadIdx.x, feat, Win, Wsrc, Wdst,
              featH, WinT, WT, cnt, hg);
}
__global__ void count_kernel(const int* src, const int* dst, int* cnt) {
    int e = blockIdx.x * blockDim.x + threadIdx.x;
    if (e < N_EDGES) atomicAdd(&cnt[dst[e] * NBKT + (src[e] >> 12)], 1);
}
__global__ __launch_bounds__(256) void scanp_kernel(const int* cnt, int* bsum) {
    __shared__ int si[4];
    scanp_unit(blockIdx.x, threadIdx.x, cnt, bsum, si);
}
__global__ __launch_bounds__(256) void scans_kernel(const int* cnt, const int* bsum,
                                                    int* offs, int* cursor) {
    __shared__ int si[4];
    scans_unit(blockIdx.x, threadIdx.x, cnt, bsum, offs, cursor, si);
}
__global__ void fill_kernel(const int* src, const int* dst, int* cursor, int* csr_src) {
    int e = blockIdx.x * blockDim.x + threadIdx.x;
    if (e < N_EDGES) {
        int sv = src[e];
        int p = atomicAdd(&cursor[dst[e] * NBKT + (sv >> 12)], 1);
        csr_src[p] = sv;
    }
}
template <int DUAL>
__global__ __launch_bounds__(256, 4) void gemm_kernel(
    const unsigned short* Ah, const unsigned short* BT1, const float* bias1,
    unsigned short* O1, const unsigned short* BT2, const float* bias2,
    unsigned short* O2, int M, int K, int N) {
    __shared__ __align__(16) unsigned short smem[20480];
    gemm_tile<DUAL>(blockIdx.x, blockIdx.y, threadIdx.x, Ah, BT1, bias1, O1,
                    BT2, bias2, O2, M, K, N, smem, smem + 4096, smem + 12288);
}
__global__ __launch_bounds__(256) void agg_kernel(const unsigned short* fsb,
                                                  const unsigned short* fdb,
                                                  unsigned short* hb, const int* offs,
                                                  const int* csr_src, const float* attn_l) {
    agg_unit(blockIdx.x, threadIdx.x, fsb, fdb, hb, offs, csr_src, attn_l);
}
__global__ __launch_bounds__(256) void pool_kernel(const unsigned short* hb, const int* gid,
                                                   float* hg) {
    pool_unit(blockIdx.x, threadIdx.x, hb, gid, hg);
}
__global__ __launch_bounds__(256) void cls_kernel(const float* hg,
                                                  const float* Wc1, const float* bc1,
                                                  const float* Wc2, const float* bc2,
                                                  const float* Wc3, const float* bc3,
                                                  float* out) {
    __shared__ float sf[HID * 2 + HID / 2];
    cls_unit(blockIdx.x, threadIdx.x, sf, hg, Wc1, bc1, Wc2, bc2, Wc3, bc3, out);
}

// ---------------- launch ----------------
extern "C" void kernel_launch(void* const* d_in, const int* in_sizes, int n_in,
                              void* d_out, int out_size, void* d_ws, size_t ws_size,
                              hipStream_t stream) {
    const float* feature = (const float*)d_in[0];
    const float* W_in   = (const float*)d_in[1];
    const float* b_in   = (const float*)d_in[2];
    const float* W_src  = (const float*)d_in[3];
    const float* b_src  = (const float*)d_in[4];
    const float* W_dst  = (const float*)d_in[5];
    const float* b_dst  = (const float*)d_in[6];
    const float* attn   = (const float*)d_in[7];
    const float* Wc1    = (const float*)d_in[8];
    const float* bc1    = (const float*)d_in[9];
    const float* Wc2    = (const float*)d_in[10];
    const float* bc2    = (const float*)d_in[11];
    const float* Wc3    = (const float*)d_in[12];
    const float* bc3    = (const float*)d_in[13];
    const int* src     = (const int*)d_in[14];
    const int* dst     = (const int*)d_in[15];
    const int* gid     = (const int*)d_in[16];
    float* out = (float*)d_out;

    char* w = (char*)d_ws;
    auto alloc = [&](size_t bytes) -> void* {
        void* p = (void*)w;
        w += (bytes + 255) & ~(size_t)255;
        return p;
    };
    unsigned short* hb  = (unsigned short*)alloc((size_t)N_NODES * HID * 2);
    unsigned short* fsb = (unsigned short*)alloc((size_t)N_NODES * HID * 2);
    unsigned short* fdb = (unsigned short*)alloc((size_t)N_NODES * HID * 2);
    float* hg    = (float*)alloc((size_t)NUM_GRAPHS * HID * 4);
    int* cnt     = (int*)alloc((size_t)N_BINS * 4);
    int* offs    = (int*)alloc((size_t)(N_BINS + 1) * 4);
    int* cursor  = (int*)alloc((size_t)N_BINS * 4);
    int* csr_src = (int*)alloc((size_t)N_EDGES * 4);
    int* bsum    = (int*)alloc((size_t)N_SCB * 4);
    unsigned short* WinT = (unsigned short*)alloc((size_t)IN_DIM * HID * 2);
    unsigned short* WT   = (unsigned short*)alloc((size_t)6 * HID * HID * 2);
    unsigned short* featH = (unsigned short*)alloc((size_t)N_NODES * IN_DIM * 2);
    (void)alloc(4096);  // slack for clamped staging overreach

    MegaParams mp;
    mp.feature = feature; mp.W_in = W_in; mp.b_in = b_in;
    mp.W_src = W_src; mp.b_src = b_src; mp.W_dst = W_dst; mp.b_dst = b_dst;
    mp.attn = attn;
    mp.Wc1 = Wc1; mp.bc1 = bc1; mp.Wc2 = Wc2; mp.bc2 = bc2; mp.Wc3 = Wc3; mp.bc3 = bc3;
    mp.src = src; mp.dst = dst; mp.gid = gid;
    mp.out = out;
    mp.hb = hb; mp.fsb = fsb; mp.fdb = fdb;
    mp.hg = hg; mp.cnt = cnt; mp.offs = offs; mp.cursor = cursor; mp.csr_src = csr_src;
    mp.bsum = bsum; mp.WinT = WinT; mp.WT = WT; mp.featH = featH;

    // Decide cooperative grid once: co-resident capacity (expect 4 blocks/CU x 256 CUs).
    static int coop_grid = -2;
    if (coop_grid == -2) {
        int dev = 0; (void)hipGetDevice(&dev);
        int sup = 0;
        (void)hipDeviceGetAttribute(&sup, hipDeviceAttributeCooperativeLaunch, dev);
        int ncu = 0;
        (void)hipDeviceGetAttribute(&ncu, hipDeviceAttributeMultiprocessorCount, dev);
        int nb = 0;
        if (sup && ncu >= 1 &&
            hipOccupancyMaxActiveBlocksPerMultiprocessor(&nb, mega_kernel, 256, 0) == hipSuccess &&
            nb >= 1) {
            long g = (long)nb * (long)ncu;
            if (g > 1024) g = 1024;
            coop_grid = (int)g;
        } else {
            coop_grid = -1;
        }
    }

    if (coop_grid > 0) {
        void* kargs[] = { (void*)&mp };
        hipError_t err = hipLaunchCooperativeKernel(mega_kernel, dim3(coop_grid), dim3(256),
                                                    kargs, 0, stream);
        if (err == hipSuccess) return;
        coop_grid = -1;  // cooperative launch rejected -> use fallback from now on
    }

    // ---------------- fallback: original 13-dispatch pipeline ----------------
    hipLaunchKernelGGL(prep_kernel, dim3((PREP_TOTAL + 255) / 256), dim3(256), 0, stream,
                       feature, W_in, W_src, W_dst, featH, WinT, WT, cnt, hg);
    hipLaunchKernelGGL(count_kernel, dim3((N_EDGES + 255) / 256), dim3(256), 0, stream,
                       src, dst, cnt);
    hipLaunchKernelGGL(scanp_kernel, dim3(N_SCB), dim3(256), 0, stream, cnt, bsum);
    hipLaunchKernelGGL(scans_kernel, dim3(N_SCB), dim3(256), 0, stream, cnt, bsum, offs, cursor);
    hipLaunchKernelGGL(fill_kernel, dim3((N_EDGES + 255) / 256), dim3(256), 0, stream,
                       src, dst, cursor, csr_src);

    dim3 ggrid(313, 2);
    hipLaunchKernelGGL((gemm_kernel<0>), ggrid, dim3(256), 0, stream,
                       featH, WinT, b_in, hb,
                       (const unsigned short*)nullptr, (const float*)nullptr,
                       (unsigned short*)nullptr, N_NODES, IN_DIM, HID);
    for (int l = 0; l < LAYERS; ++l) {
        hipLaunchKernelGGL((gemm_kernel<1>), ggrid, dim3(256), 0, stream,
                           hb, WT + (size_t)l * HID * HID, b_src + (size_t)l * HID, fsb,
                           WT + (size_t)(3 + l) * HID * HID, b_dst + (size_t)l * HID, fdb,
                           N_NODES, HID, HID);
        hipLaunchKernelGGL(agg_kernel, dim3(NAGG), dim3(256), 0, stream,
                           fsb, fdb, hb, offs, csr_src, attn + (size_t)l * HEADS * DH);
    }
    hipLaunchKernelGGL(pool_kernel, dim3(NPOOL), dim3(256), 0, stream, hb, gid, hg);
    hipLaunchKernelGGL(cls_kernel, dim3(NUM_GRAPHS), dim3(256), 0, stream,
                       hg, Wc1, bc1, Wc2, bc2, Wc3, bc3, out);
}

// Round 2
// 388.239 us; speedup vs baseline: 2.8621x; 2.8621x over previous
//
#include <hip/hip_runtime.h>
#include <hip/hip_bf16.h>
#include <math.h>

#define N_NODES 20000
#define N_EDGES 320000
#define IN_DIM 128
#define HID 256
#define HEADS 8
#define DH 32
#define LAYERS 3
#define NUM_GRAPHS 64
#define OUT_DIM 10
#define SLOPE 0.2f

// src-bucketed CSR: bucket = src >> 12 (4096 nodes = 2 MB of fsb per bucket)
#define NBKT 5
#define N_BINS (N_NODES * NBKT)      // 100000
#define N_BINS4 (N_BINS / 4)         // 25000
#define SCAN_CHUNKS ((N_BINS4 + 255) / 256)   // 98

#define GEMM_TILES 626               // 313 m-tiles x 2 n-tiles
#define COUNT_BLOCKS 1250            // 320000 / 256

typedef __bf16 bf16x8 __attribute__((ext_vector_type(8)));
typedef float f32x4 __attribute__((ext_vector_type(4)));

static __device__ __forceinline__ unsigned short f2bfbits(float v) {
    __bf16 b = (__bf16)v;
    return __builtin_bit_cast(unsigned short, b);
}
static __device__ __forceinline__ float bfu2f(unsigned short v) {
    return __builtin_bit_cast(float, ((unsigned)v) << 16);
}
// unpack 8 bf16 (in a uint4) -> 8 fp32, exact
static __device__ __forceinline__ void unpack8(uint4 u, float* f) {
    unsigned p0 = u.x, p1 = u.y, p2 = u.z, p3 = u.w;
    f[0] = __builtin_bit_cast(float, p0 << 16);
    f[1] = __builtin_bit_cast(float, p0 & 0xffff0000u);
    f[2] = __builtin_bit_cast(float, p1 << 16);
    f[3] = __builtin_bit_cast(float, p1 & 0xffff0000u);
    f[4] = __builtin_bit_cast(float, p2 << 16);
    f[5] = __builtin_bit_cast(float, p2 & 0xffff0000u);
    f[6] = __builtin_bit_cast(float, p3 << 16);
    f[7] = __builtin_bit_cast(float, p3 & 0xffff0000u);
}

// async 16B global->LDS (DMA, wave-uniform LDS base + lane*16)
typedef const __attribute__((address_space(1))) unsigned int* as1_u32p;
typedef __attribute__((address_space(3))) unsigned int* as3_u32p;
static __device__ __forceinline__ void async_cp16(const unsigned short* g, unsigned short* l) {
    __builtin_amdgcn_global_load_lds((as1_u32p)g, (as3_u32p)l, 16, 0, 0);
}

// ---------------- prep: feature cast, weight transpose/cast ----------------
#define CAST_N4 (N_NODES * IN_DIM / 4)                 // 640000
#define WTRANS_TOTAL (IN_DIM * HID + 6 * HID * HID)    // 425984
#define PREP_TOTAL (CAST_N4 + WTRANS_TOTAL)            // 1065984 = 4164 * 256
#define PREP_BLOCKS (PREP_TOTAL / 256)                 // 4164 (exact)

static __device__ void prep_item(int idx,
                                 const float* __restrict__ feat,
                                 const float* __restrict__ Win,
                                 const float* __restrict__ Wsrc,
                                 const float* __restrict__ Wdst,
                                 unsigned short* __restrict__ featH,
                                 unsigned short* __restrict__ WinT,
                                 unsigned short* __restrict__ WT) {
    if (idx < CAST_N4) {
        float4 v = ((const float4*)feat)[idx];
        ushort4 o;
        o.x = f2bfbits(v.x); o.y = f2bfbits(v.y);
        o.z = f2bfbits(v.z); o.w = f2bfbits(v.w);
        ((ushort4*)featH)[idx] = o;
    } else {
        int j = idx - CAST_N4;
        if (j < IN_DIM * HID) {
            int n = j / IN_DIM, k = j % IN_DIM;
            WinT[j] = f2bfbits(Win[k * HID + n]);
        } else {
            int r6 = j - IN_DIM * HID;
            int mat = r6 >> 16;
            int r = r6 & 65535;
            int n = r >> 8, k = r & 255;
            const float* base = (mat < 3) ? (Wsrc + (size_t)mat * 65536)
                                          : (Wdst + (size_t)(mat - 3) * 65536);
            WT[r6] = f2bfbits(base[k * 256 + n]);
        }
    }
}

// ---------------- single-block exclusive scan over 100k bins (int4, 98 chunks) ----------------
static __device__ void scan_block(const int* __restrict__ cnt, int* __restrict__ offs,
                                  int* __restrict__ cursor, int t, int* wsum) {
    int running = 0;
    const int4* c4 = (const int4*)cnt;
    for (int c = 0; c < SCAN_CHUNKS; ++c) {
        int idx4 = c * 256 + t;
        int4 x = make_int4(0, 0, 0, 0);
        if (idx4 < N_BINS4) x = c4[idx4];
        int tsum = x.x + x.y + x.z + x.w;
        int v = tsum;
#pragma unroll
        for (int d = 1; d < 64; d <<= 1) {
            int u = __shfl_up(v, d, 64);
            if ((t & 63) >= d) v += u;
        }
        if ((t & 63) == 63) wsum[t >> 6] = v;
        __syncthreads();
        int w0 = wsum[0], w1 = wsum[1], w2 = wsum[2], w3 = wsum[3];
        int wid = t >> 6;
        int waveoff = 0;
        if (wid > 0) waveoff += w0;
        if (wid > 1) waveoff += w1;
        if (wid > 2) waveoff += w2;
        int ex = running + waveoff + (v - tsum);
        if (idx4 < N_BINS4) {
            int4 o;
            o.x = ex; o.y = ex + x.x; o.z = o.y + x.y; o.w = o.z + x.z;
            ((int4*)offs)[idx4] = o;
            ((int4*)cursor)[idx4] = o;
        }
        running += w0 + w1 + w2 + w3;
        __syncthreads();   // protect wsum reuse next chunk
    }
    if (t == 0) offs[N_BINS] = running;
}

// ---------------- MFMA GEMM tile: bf16 A, M64 x N128, BK=32 (proven round-0 code) ----------------
template <int DUAL>
static __device__ void gemm_tile(int mt, int nt, int t,
                                 const unsigned short* __restrict__ Ah,
                                 const unsigned short* __restrict__ BT1,
                                 const float* __restrict__ bias1,
                                 unsigned short* __restrict__ O1,
                                 const unsigned short* __restrict__ BT2,
                                 const float* __restrict__ bias2,
                                 unsigned short* __restrict__ O2,
                                 int M, int K, int N,
                                 unsigned short* AsP, unsigned short* Bs1P,
                                 unsigned short* Bs2P) {
    const int wv = t >> 6, lane = t & 63, quad = lane >> 4, l15 = lane & 15;
    const int m0 = mt * 64, n0 = nt * 128;

    const int sA = wv * 64 + lane;
    const int rA = sA >> 2, cA = (sA & 3) ^ ((rA >> 1) & 3);
    int gmA = m0 + rA; if (gmA >= M) gmA = M - 1;
    const size_t offA = (size_t)gmA * K + cA * 8;
    const int sB0 = wv * 64 + lane, sB1v = sB0 + 256;
    const int rB0 = sB0 >> 2, cB0 = (sB0 & 3) ^ ((rB0 >> 1) & 3);
    const int rB1 = sB1v >> 2, cB1 = (sB1v & 3) ^ ((rB1 >> 1) & 3);
    const size_t offB0 = (size_t)(n0 + rB0) * K + cB0 * 8;
    const size_t offB1 = (size_t)(n0 + rB1) * K + cB1 * 8;

    auto issue = [&](int buf, int k0) {
        async_cp16(Ah + offA + k0, AsP + buf * 2048 + wv * 512);
        async_cp16(BT1 + offB0 + k0, Bs1P + buf * 4096 + wv * 512);
        async_cp16(BT1 + offB1 + k0, Bs1P + buf * 4096 + 2048 + wv * 512);
        if (DUAL) {
            async_cp16(BT2 + offB0 + k0, Bs2P + buf * 4096 + wv * 512);
            async_cp16(BT2 + offB1 + k0, Bs2P + buf * 4096 + 2048 + wv * 512);
        }
    };

    const int mrow0 = (wv >> 1) * 32;
    const int ncb = (wv & 1) * 64;

    f32x4 zero = {0.f, 0.f, 0.f, 0.f};
    f32x4 acc1[2][4], acc2[2][4];
#pragma unroll
    for (int mi = 0; mi < 2; ++mi)
#pragma unroll
        for (int t4 = 0; t4 < 4; ++t4) { acc1[mi][t4] = zero; acc2[mi][t4] = zero; }

    issue(0, 0);
    int buf = 0;
    for (int k0 = 0; k0 < K; k0 += 32, buf ^= 1) {
        __syncthreads();
        if (k0 + 32 < K) issue(buf ^ 1, k0 + 32);

        bf16x8 aF[2];
#pragma unroll
        for (int mi = 0; mi < 2; ++mi) {
            int row = mrow0 + mi * 16 + l15;
            int aoff = row * 32 + ((quad ^ ((row >> 1) & 3)) << 3);
            aF[mi] = __builtin_bit_cast(bf16x8, *(const uint4*)(AsP + buf * 2048 + aoff));
        }
#pragma unroll
        for (int t4 = 0; t4 < 4; ++t4) {
            int brow = ncb + t4 * 16 + l15;
            int boff = brow * 32 + ((quad ^ ((brow >> 1) & 3)) << 3);
            bf16x8 b1 = __builtin_bit_cast(bf16x8, *(const uint4*)(Bs1P + buf * 4096 + boff));
#pragma unroll
            for (int mi = 0; mi < 2; ++mi)
                acc1[mi][t4] = __builtin_amdgcn_mfma_f32_16x16x32_bf16(aF[mi], b1, acc1[mi][t4], 0, 0, 0);
            if (DUAL) {
                bf16x8 b2 = __builtin_bit_cast(bf16x8, *(const uint4*)(Bs2P + buf * 4096 + boff));
#pragma unroll
                for (int mi = 0; mi < 2; ++mi)
                    acc2[mi][t4] = __builtin_amdgcn_mfma_f32_16x16x32_bf16(aF[mi], b2, acc2[mi][t4], 0, 0, 0);
            }
        }
    }

    float bia1[4], bia2[4];
#pragma unroll
    for (int t4 = 0; t4 < 4; ++t4) {
        bia1[t4] = bias1[n0 + ncb + t4 * 16 + l15];
        bia2[t4] = DUAL ? bias2[n0 + ncb + t4 * 16 + l15] : 0.f;
    }
#pragma unroll
    for (int mi = 0; mi < 2; ++mi) {
#pragma unroll
        for (int t4 = 0; t4 < 4; ++t4) {
            int gn = n0 + ncb + t4 * 16 + l15;
#pragma unroll
            for (int r = 0; r < 4; ++r) {
                int gm = m0 + mrow0 + mi * 16 + quad * 4 + r;
                if (gm < M) {
                    float v = acc1[mi][t4][r] + bia1[t4];
                    O1[(size_t)gm * N + gn] = f2bfbits(v);
                    if (DUAL) {
                        float v2 = acc2[mi][t4][r] + bia2[t4];
                        O2[(size_t)gm * N + gn] = f2bfbits(v2);
                    }
                }
            }
        }
    }
}

// ---------------- GATv2 aggregation (proven round-0 code, 8 nodes / 256 threads) ----------------
static __device__ void agg_unit(int u, int t,
                                const unsigned short* __restrict__ fsb,
                                const unsigned short* __restrict__ fdb,
                                unsigned short* __restrict__ hb,
                                const int* __restrict__ offs,
                                const int* __restrict__ csr_src,
                                const float* __restrict__ attn_l) {
    int node = u * 8 + (t >> 5);
    if (node >= N_NODES) return;
    int l32 = t & 31;
    int dbase = l32 * 8;
    int abase = (l32 >> 2) * DH + (l32 & 3) * 8;

    float a[8];
#pragma unroll
    for (int j = 0; j < 8; ++j) a[j] = attn_l[abase + j];

    float fdv[8];
    unpack8(*(const uint4*)(fdb + (size_t)node * HID + dbase), fdv);

    float ssum0 = 0.f, ssum1 = 0.f;
    float acc0[8], acc1[8];
#pragma unroll
    for (int j = 0; j < 8; ++j) { acc0[j] = 0.f; acc1[j] = 0.f; }

    auto procE = [&](uint4 uu, float* acc, float& ssum) {
        float fsv[8];
        unpack8(uu, fsv);
        float p = 0.f;
#pragma unroll
        for (int j = 0; j < 8; ++j) {
            float e = fsv[j] + fdv[j];
            e = fmaxf(e, SLOPE * e);   // leakyrelu (slope<1)
            p += e * a[j];
        }
        p += __shfl_xor(p, 1, 64);
        p += __shfl_xor(p, 2, 64);
        float w = __expf(p);
        ssum += w;
#pragma unroll
        for (int j = 0; j < 8; ++j) acc[j] += w * fsv[j];
    };

    const unsigned short* fsl = fsb + dbase;
    int beg = offs[node * NBKT], end = offs[node * NBKT + NBKT];
    int nfull = (end - beg) >> 2;
    const int limit = beg + nfull * 4;

    uint4 cu0, cu1, cu2, cu3;
    int ci0, ci1, ci2, ci3;
    int base = beg + 8;
    bool have = (nfull >= 1);
    bool haveN = (nfull >= 2);
    if (have) {
        int s0 = csr_src[beg], s1 = csr_src[beg + 1];
        int s2 = csr_src[beg + 2], s3 = csr_src[beg + 3];
        if (haveN) {
            ci0 = csr_src[beg + 4]; ci1 = csr_src[beg + 5];
            ci2 = csr_src[beg + 6]; ci3 = csr_src[beg + 7];
        }
        cu0 = *(const uint4*)(fsl + (size_t)s0 * HID);
        cu1 = *(const uint4*)(fsl + (size_t)s1 * HID);
        cu2 = *(const uint4*)(fsl + (size_t)s2 * HID);
        cu3 = *(const uint4*)(fsl + (size_t)s3 * HID);
    }
    while (have) {
        uint4 nu0, nu1, nu2, nu3;
        int ni0, ni1, ni2, ni3;
        if (haveN) {
            nu0 = *(const uint4*)(fsl + (size_t)ci0 * HID);
            nu1 = *(const uint4*)(fsl + (size_t)ci1 * HID);
            nu2 = *(const uint4*)(fsl + (size_t)ci2 * HID);
            nu3 = *(const uint4*)(fsl + (size_t)ci3 * HID);
        }
        bool haveNN = (base + 4 <= limit);
        if (haveNN) {
            ni0 = csr_src[base]; ni1 = csr_src[base + 1];
            ni2 = csr_src[base + 2]; ni3 = csr_src[base + 3];
        }
        base += 4;
        procE(cu0, acc0, ssum0);
        procE(cu1, acc1, ssum1);
        procE(cu2, acc0, ssum0);
        procE(cu3, acc1, ssum1);
        if (haveN) { cu0 = nu0; cu1 = nu1; cu2 = nu2; cu3 = nu3; }
        if (haveNN) { ci0 = ni0; ci1 = ni1; ci2 = ni2; ci3 = ni3; }
        have = haveN; haveN = haveNN;
    }
    for (int idx = limit; idx < end; ++idx) {
        int sv = csr_src[idx];
        procE(*(const uint4*)(fsl + (size_t)sv * HID), acc0, ssum0);
    }

    float ssum = ssum0 + ssum1;
    float acc[8];
#pragma unroll
    for (int j = 0; j < 8; ++j) acc[j] = acc0[j] + acc1[j];

    float inv = ssum > 0.f ? 1.f / ssum : 0.f;
    float hv[8];
    unpack8(*(const uint4*)(hb + (size_t)node * HID + dbase), hv);
    unsigned short ob[8];
#pragma unroll
    for (int j = 0; j < 8; ++j) {
        float o = fmaxf(acc[j] * inv + hv[j], 0.f);
        ob[j] = f2bfbits(o);
    }
    *(uint4*)(hb + (size_t)node * HID + dbase) = *(uint4*)ob;
}

// ---------------- D1: prep || count ----------------
__global__ void prep_count_kernel(const float* __restrict__ feat,
                                  const float* __restrict__ Win,
                                  const float* __restrict__ Wsrc,
                                  const float* __restrict__ Wdst,
                                  unsigned short* __restrict__ featH,
                                  unsigned short* __restrict__ WinT,
                                  unsigned short* __restrict__ WT,
                                  const int* __restrict__ src,
                                  const int* __restrict__ dst,
                                  int* __restrict__ cnt) {
    int bid = blockIdx.x;
    if (bid < PREP_BLOCKS) {
        prep_item(bid * 256 + threadIdx.x, feat, Win, Wsrc, Wdst, featH, WinT, WT);
    } else {
        int e = (bid - PREP_BLOCKS) * 256 + threadIdx.x;
        if (e < N_EDGES) atomicAdd(&cnt[dst[e] * NBKT + (src[e] >> 12)], 1);
    }
}

// ---------------- D2: input-projection GEMM || single-block scan ----------------
__global__ __launch_bounds__(256, 4) void gemm0_scan_kernel(
    const unsigned short* __restrict__ featH, const unsigned short* __restrict__ WinT,
    const float* __restrict__ b_in, unsigned short* __restrict__ hb,
    const int* __restrict__ cnt, int* __restrict__ offs, int* __restrict__ cursor) {
    __shared__ __align__(16) unsigned short smem[20480];
    int bid = blockIdx.x;
    if (bid < GEMM_TILES) {
        gemm_tile<0>(bid >> 1, bid & 1, threadIdx.x, featH, WinT, b_in, hb,
                     (const unsigned short*)nullptr, (const float*)nullptr,
                     (unsigned short*)nullptr, N_NODES, IN_DIM, HID,
                     smem, smem + 4096, smem + 12288);
    } else {
        scan_block(cnt, offs, cursor, threadIdx.x, (int*)(void*)smem);
    }
}

// ---------------- D3: layer-0 dual GEMM || CSR fill ----------------
__global__ __launch_bounds__(256, 4) void gemm1_fill_kernel(
    const unsigned short* __restrict__ hb,
    const unsigned short* __restrict__ WTs, const float* __restrict__ bs,
    unsigned short* __restrict__ fsb,
    const unsigned short* __restrict__ WTd, const float* __restrict__ bd,
    unsigned short* __restrict__ fdb,
    const int* __restrict__ src, const int* __restrict__ dst,
    int* __restrict__ cursor, int* __restrict__ csr_src) {
    __shared__ __align__(16) unsigned short smem[20480];
    int bid = blockIdx.x;
    if (bid < GEMM_TILES) {
        gemm_tile<1>(bid >> 1, bid & 1, threadIdx.x, hb, WTs, bs, fsb, WTd, bd, fdb,
                     N_NODES, HID, HID, smem, smem + 4096, smem + 12288);
    } else {
        int e = (bid - GEMM_TILES) * 256 + threadIdx.x;
        if (e < N_EDGES) {
            int sv = src[e];
            int p = atomicAdd(&cursor[dst[e] * NBKT + (sv >> 12)], 1);
            csr_src[p] = sv;
        }
    }
}

// ---------------- standalone dual GEMM (layers 1,2) ----------------
__global__ __launch_bounds__(256, 4) void gemm_kernel(
    const unsigned short* __restrict__ Ah,
    const unsigned short* __restrict__ BT1, const float* __restrict__ bias1,
    unsigned short* __restrict__ O1,
    const unsigned short* __restrict__ BT2, const float* __restrict__ bias2,
    unsigned short* __restrict__ O2) {
    __shared__ __align__(16) unsigned short smem[20480];
    gemm_tile<1>(blockIdx.x, blockIdx.y, threadIdx.x, Ah, BT1, bias1, O1,
                 BT2, bias2, O2, N_NODES, HID, HID, smem, smem + 4096, smem + 12288);
}

// ---------------- aggregation dispatch ----------------
__global__ __launch_bounds__(256) void agg_kernel(const unsigned short* __restrict__ fsb,
                                                  const unsigned short* __restrict__ fdb,
                                                  unsigned short* __restrict__ hb,
                                                  const int* __restrict__ offs,
                                                  const int* __restrict__ csr_src,
                                                  const float* __restrict__ attn_l) {
    agg_unit(blockIdx.x, threadIdx.x, fsb, fdb, hb, offs, csr_src, attn_l);
}

// ---------------- D9: fused pool + classifier (one block per graph) ----------------
__global__ __launch_bounds__(256) void poolcls_kernel(
    const unsigned short* __restrict__ hb, const int* __restrict__ gid,
    const float* __restrict__ Wc1, const float* __restrict__ bc1,
    const float* __restrict__ Wc2, const float* __restrict__ bc2,
    const float* __restrict__ Wc3, const float* __restrict__ bc3,
    float* __restrict__ out) {
    __shared__ float xin[HID];
    __shared__ float x1[HID];
    __shared__ float x2[HID / 2];
    int g = blockIdx.x, t = threadIdx.x;

    // node range of graph g in sorted gid: [s0, e0)
    int lo = 0, hi = N_NODES;
    while (lo < hi) { int mid = (lo + hi) >> 1; if (gid[mid] < g) lo = mid + 1; else hi = mid; }
    int s0 = lo;
    hi = N_NODES;
    while (lo < hi) { int mid = (lo + hi) >> 1; if (gid[mid] < g + 1) lo = mid + 1; else hi = mid; }
    int e0 = lo;

    // pool: thread t sums feature t over the graph's nodes (4-way ILP)
    float a0 = 0.f, a1 = 0.f, a2 = 0.f, a3 = 0.f;
    int n = s0;
    for (; n + 4 <= e0; n += 4) {
        a0 += bfu2f(hb[(size_t)(n + 0) * HID + t]);
        a1 += bfu2f(hb[(size_t)(n + 1) * HID + t]);
        a2 += bfu2f(hb[(size_t)(n + 2) * HID + t]);
        a3 += bfu2f(hb[(size_t)(n + 3) * HID + t]);
    }
    for (; n < e0; ++n) a0 += bfu2f(hb[(size_t)n * HID + t]);
    xin[t] = (a0 + a1) + (a2 + a3);
    __syncthreads();

    {
        float acc = bc1[t];
        for (int k = 0; k < HID; ++k) acc += xin[k] * Wc1[k * HID + t];
        x1[t] = fmaxf(acc, 0.f);
    }
    __syncthreads();
    if (t < HID / 2) {
        float acc = bc2[t];
        for (int k = 0; k < HID; ++k) acc += x1[k] * Wc2[k * (HID / 2) + t];
        x2[t] = fmaxf(acc, 0.f);
    }
    __syncthreads();
    if (t < OUT_DIM) {
        float acc = bc3[t];
        for (int k = 0; k < HID / 2; ++k) acc += x2[k] * Wc3[k * OUT_DIM + t];
        out[g * OUT_DIM + t] = acc;
    }
}

// ---------------- launch: 10 dispatches (memset + 9 kernels) ----------------
extern "C" void kernel_launch(void* const* d_in, const int* in_sizes, int n_in,
                              void* d_out, int out_size, void* d_ws, size_t ws_size,
                              hipStream_t stream) {
    const float* feature = (const float*)d_in[0];
    const float* W_in   = (const float*)d_in[1];
    const float* b_in   = (const float*)d_in[2];
    const float* W_src  = (const float*)d_in[3];
    const float* b_src  = (const float*)d_in[4];
    const float* W_dst  = (const float*)d_in[5];
    const float* b_dst  = (const float*)d_in[6];
    const float* attn   = (const float*)d_in[7];
    const float* Wc1    = (const float*)d_in[8];
    const float* bc1    = (const float*)d_in[9];
    const float* Wc2    = (const float*)d_in[10];
    const float* bc2    = (const float*)d_in[11];
    const float* Wc3    = (const float*)d_in[12];
    const float* bc3    = (const float*)d_in[13];
    const int* src     = (const int*)d_in[14];
    const int* dst     = (const int*)d_in[15];
    const int* gid     = (const int*)d_in[16];
    float* out = (float*)d_out;

    char* w = (char*)d_ws;
    auto alloc = [&](size_t bytes) -> void* {
        void* p = (void*)w;
        w += (bytes + 255) & ~(size_t)255;
        return p;
    };
    unsigned short* hb  = (unsigned short*)alloc((size_t)N_NODES * HID * 2);  // unified bf16 h
    unsigned short* fsb = (unsigned short*)alloc((size_t)N_NODES * HID * 2);
    unsigned short* fdb = (unsigned short*)alloc((size_t)N_NODES * HID * 2);
    int* cnt     = (int*)alloc((size_t)N_BINS * 4);
    int* offs    = (int*)alloc((size_t)(N_BINS + 4) * 4);
    int* cursor  = (int*)alloc((size_t)N_BINS * 4);
    int* csr_src = (int*)alloc((size_t)N_EDGES * 4);
    unsigned short* WinT = (unsigned short*)alloc((size_t)IN_DIM * HID * 2);
    unsigned short* WT   = (unsigned short*)alloc((size_t)6 * HID * HID * 2);
    unsigned short* featH = (unsigned short*)alloc((size_t)N_NODES * IN_DIM * 2);
    (void)alloc(4096);  // slack for clamped staging overreach

    // D0: zero the count bins (replaces prep's zero phase; unlocks prep||count fusion)
    hipMemsetAsync(cnt, 0, (size_t)N_BINS * 4, stream);

    // D1: prep (feature cast + weight transposes) || edge-bin count
    hipLaunchKernelGGL(prep_count_kernel, dim3(PREP_BLOCKS + COUNT_BLOCKS), dim3(256), 0, stream,
                       feature, W_in, W_src, W_dst, featH, WinT, WT, src, dst, cnt);

    // D2: input-projection GEMM || single-block hierarchical scan
    hipLaunchKernelGGL(gemm0_scan_kernel, dim3(GEMM_TILES + 1), dim3(256), 0, stream,
                       featH, WinT, b_in, hb, cnt, offs, cursor);

    // D3: layer-0 dual GEMM || CSR fill
    hipLaunchKernelGGL(gemm1_fill_kernel, dim3(GEMM_TILES + COUNT_BLOCKS), dim3(256), 0, stream,
                       hb, WT, b_src, fsb, WT + 3 * 65536, b_dst, fdb,
                       src, dst, cursor, csr_src);

    // D4..D8: agg0, gemm_l1, agg1, gemm_l2, agg2
    for (int l = 0; l < LAYERS; ++l) {
        hipLaunchKernelGGL(agg_kernel, dim3(N_NODES / 8), dim3(256), 0, stream,
                           fsb, fdb, hb, offs, csr_src, attn + (size_t)l * HEADS * DH);
        if (l + 1 < LAYERS) {
            hipLaunchKernelGGL(gemm_kernel, dim3(313, 2), dim3(256), 0, stream,
                               hb, WT + (size_t)(l + 1) * 65536, b_src + (size_t)(l + 1) * HID, fsb,
                               WT + (size_t)(4 + l) * 65536, b_dst + (size_t)(l + 1) * HID, fdb);
        }
    }

    // D9: fused graph-sum-pool + classifier
    hipLaunchKernelGGL(poolcls_kernel, dim3(NUM_GRAPHS), dim3(256), 0, stream,
                       hb, gid, Wc1, bc1, Wc2, bc2, Wc3, bc3, out);
}